// Round 6
// baseline (208.305 us; speedup 1.0000x reference)
//
#include <hip/hip_runtime.h>

typedef __bf16 bf16x8 __attribute__((ext_vector_type(8)));
typedef float f32x4 __attribute__((ext_vector_type(4)));

constexpr int B = 4, S = 4096, D = 256;
// log2(e) / sqrt(D) = 1.4426950408889634 / 16
constexpr float CSC = 0.09016844005556021f;

static __device__ __forceinline__ unsigned short f2bf(float f) {
  unsigned int u = __builtin_bit_cast(unsigned int, f);
  u = (u + 0x7fffu + ((u >> 16) & 1u)) >> 16;
  return (unsigned short)u;
}

static __device__ __forceinline__ float bf2f(unsigned short u) {
  unsigned int v = ((unsigned int)u) << 16;
  return __builtin_bit_cast(float, v);
}

// pack two f32 -> 2x bf16 (RNE), low half = lo
static __device__ __forceinline__ unsigned int pk2bf(float lo, float hi) {
  unsigned int r;
  asm("v_cvt_pk_bf16_f32 %0, %1, %2" : "=v"(r) : "v"(lo), "v"(hi));
  return r;
}

// async global->LDS, 16B per lane; LDS dest = wave-uniform base + lane*16
static __device__ __forceinline__ void gld16(const void* g, void* l) {
  __builtin_amdgcn_global_load_lds(
      (const __attribute__((address_space(1))) unsigned int*)g,
      (__attribute__((address_space(3))) unsigned int*)l, 16, 0, 0);
}

// ---- kernel 1: cast x -> bf16, and build xT[b][d][s] (bf16) ----
__global__ __launch_bounds__(256) void k_prep(const float* __restrict__ x,
                                              unsigned short* __restrict__ xbf,
                                              unsigned short* __restrict__ xT) {
  __shared__ unsigned short T[64][65];
  int bid = blockIdx.x;
  int b = bid >> 8, rem = bid & 255;
  int s0 = (rem >> 2) * 64, d0 = (rem & 3) * 64;
  int j = threadIdx.x & 63, i0 = threadIdx.x >> 6;
#pragma unroll
  for (int k = 0; k < 16; ++k) {
    int i = k * 4 + i0;
    int idx = (b * S + s0 + i) * D + d0 + j;
    unsigned short v = f2bf(x[idx]);
    xbf[idx] = v;
    T[j][i] = v;  // T[d_local][s_local]
  }
  __syncthreads();
#pragma unroll
  for (int k = 0; k < 16; ++k) {
    int i = k * 4 + i0;  // d_local row
    xT[(b * D + d0 + i) * S + s0 + j] = T[i][j];
  }
}

// ---- kernel 2: w_int -> bf16 (integers < 256 are exact in bf16) ----
__global__ __launch_bounds__(256) void k_deqw(const int* __restrict__ w,
                                              unsigned short* __restrict__ wbf) {
  int i = blockIdx.x * 256 + threadIdx.x;
  wbf[i] = f2bf((float)w[i]);
}

// ---- kernel 3: flash attention, 8 waves (2/SIMD), Q=32/wave, split-KV x4 ----
// 256 blocks = 64 q-groups (256 rows) x 4 kv-quarters (1024 kv = 16 tiles).
// LDS: K 2x32K + V^T 2x32K + P 8x4K = 160 KiB exactly (P uses XOR swizzle,
// stride 128B, no pad). Swapped QK^T, bf16 P via cvt_pk, defer-max THR=8,
// setprio(1) around MFMA clusters (pays at 2 waves/SIMD).
__global__ __launch_bounds__(512, 2) void k_attn(const unsigned short* __restrict__ xbf,
                                                 const unsigned short* __restrict__ xT,
                                                 unsigned short* __restrict__ attnPO0,
                                                 unsigned short* __restrict__ PO123,
                                                 float* __restrict__ ML) {
  __shared__ __align__(16) unsigned short Kb[2][64 * 256];  // 32KB x2
  __shared__ __align__(16) unsigned short Vb[2][256 * 64];  // 32KB x2 (V^T: [d][kv])
  __shared__ __align__(16) unsigned short PW[8][32 * 64];   // per-wave P bf16, swizzled

  int tid = threadIdx.x;
  int w = tid >> 6, lane = tid & 63;
  int g = lane >> 4, c = lane & 15;
  int kco = (c & 7) << 4;  // read-side XOR swizzle (bytes)

  int bid = blockIdx.x;
  int swz = (bid & 7) * 32 + (bid >> 3);  // bijective XCD swizzle (256 % 8 == 0)
  int h = swz & 3;        // kv quarter
  int qg = swz >> 2;      // q-group 0..63
  int q0 = qg * 256;      // global q row base
  int bat = q0 >> 12;     // batch
  int qloc = q0 & (S - 1);
  int kvbase = h * 1024;  // in-batch kv start

  const unsigned short* Xb = xbf + (size_t)bat * (S * D);
  const unsigned short* XTb = xT + (size_t)bat * (D * S);

  int qw = qloc + w * 32;  // wave's first q row (in-batch)

  // Q fragments: 2 q-sets of 16 rows
  bf16x8 qf[2][8];
#pragma unroll
  for (int qs = 0; qs < 2; ++qs)
#pragma unroll
    for (int dk = 0; dk < 8; ++dk)
      qf[qs][dk] = *(const bf16x8*)(Xb + (qw + qs * 16 + c) * D + dk * 32 + g * 8);

  const f32x4 zero = {0.f, 0.f, 0.f, 0.f};
  f32x4 acc[2][16];
#pragma unroll
  for (int qs = 0; qs < 2; ++qs)
#pragma unroll
    for (int i = 0; i < 16; ++i) acc[qs][i] = zero;
  float m_r[2] = {-1e30f, -1e30f};
  float l_r[2] = {0.f, 0.f};

  unsigned short* Pw = PW[w];

  // stage one KV tile (kv0 in-batch) into buffer bb; wave w does its eighth
  auto STAGE = [&](int kv0, int bb) {
#pragma unroll
    for (int i = 0; i < 4; ++i) {  // K rows w*8 .. +7, 2 rows/instr
      int r = w * 8 + i * 2 + (lane >> 5);
      int sc = ((lane & 31) * 16) ^ ((r & 7) << 4);
      gld16((const char*)Xb + (size_t)(kv0 + r) * 512 + sc,
            (char*)Kb[bb] + (w * 8 + i * 2) * 512);
    }
#pragma unroll
    for (int i = 0; i < 4; ++i) {  // V^T d-rows w*32 .. +31, 8 rows/instr
      int dr = w * 32 + i * 8 + (lane >> 3);
      int sc = ((lane & 7) * 16) ^ ((dr & 7) << 4);
      gld16((const char*)XTb + (size_t)dr * 8192 + kv0 * 2 + sc,
            (char*)Vb[bb] + (w * 32 + i * 8) * 128);
    }
  };

  STAGE(kvbase, 0);
  __syncthreads();

  constexpr int NT = 1024 / 64;  // 16 tiles per kv quarter
  for (int it = 0; it < NT; ++it) {
    int bb = it & 1;
    if (it + 1 < NT) STAGE(kvbase + (it + 1) * 64, bb ^ 1);

    // ---- QK^T (swapped): st[qs][tt][r] = S[kv=16tt+4g+r][q=qs*16+c]
    f32x4 st[2][4];
    __builtin_amdgcn_s_setprio(1);
#pragma unroll
    for (int tt = 0; tt < 4; ++tt) {
      st[0][tt] = zero;
      st[1][tt] = zero;
#pragma unroll
      for (int dk = 0; dk < 8; ++dk) {
        bf16x8 kf = *(const bf16x8*)&Kb[bb][(tt * 16 + c) * 256 +
                                            (((dk * 64 + g * 16) ^ kco) >> 1)];
        st[0][tt] = __builtin_amdgcn_mfma_f32_16x16x32_bf16(kf, qf[0][dk], st[0][tt], 0, 0, 0);
        st[1][tt] = __builtin_amdgcn_mfma_f32_16x16x32_bf16(kf, qf[1][dk], st[1][tt], 0, 0, 0);
      }
    }
    __builtin_amdgcn_s_setprio(0);

    // ---- online softmax (row = c domain)
    float tm[2];
#pragma unroll
    for (int qs = 0; qs < 2; ++qs) {
      float t0 = fmaxf(fmaxf(st[qs][0][0], st[qs][0][1]), fmaxf(st[qs][0][2], st[qs][0][3]));
      float t1 = fmaxf(fmaxf(st[qs][1][0], st[qs][1][1]), fmaxf(st[qs][1][2], st[qs][1][3]));
      float t2 = fmaxf(fmaxf(st[qs][2][0], st[qs][2][1]), fmaxf(st[qs][2][2], st[qs][2][3]));
      float t3 = fmaxf(fmaxf(st[qs][3][0], st[qs][3][1]), fmaxf(st[qs][3][2], st[qs][3][3]));
      float t = fmaxf(fmaxf(t0, t1), fmaxf(t2, t3));
      t = fmaxf(t, __shfl_xor(t, 16, 64));
      t = fmaxf(t, __shfl_xor(t, 32, 64));
      tm[qs] = t;
    }
    // defer-max: rescale only when the new tile max exceeds m by THR=8
    bool need = (tm[0] > m_r[0] + 8.f) || (tm[1] > m_r[1] + 8.f);
    if (__any(need)) {
      float mn0 = fmaxf(m_r[0], tm[0]);
      float mn1 = fmaxf(m_r[1], tm[1]);
      float cr0 = exp2f((m_r[0] - mn0) * CSC);
      float cr1 = exp2f((m_r[1] - mn1) * CSC);
      m_r[0] = mn0; m_r[1] = mn1;
      l_r[0] *= cr0; l_r[1] *= cr1;
      // redistribute corr from row=c domain to acc-row (4g+r) domain
#pragma unroll
      for (int r = 0; r < 4; ++r) {
        float ca0 = __shfl(cr0, 4 * g + r, 64);
        float ca1 = __shfl(cr1, 4 * g + r, 64);
#pragma unroll
        for (int dc = 0; dc < 16; ++dc) {
          acc[0][dc][r] *= ca0;
          acc[1][dc][r] *= ca1;
        }
      }
    }

    // ---- P = exp2(st - m), sum, write bf16 to LDS (XOR-swizzled, stride 128B)
    float ts[2] = {0.f, 0.f};
#pragma unroll
    for (int qs = 0; qs < 2; ++qs) {
#pragma unroll
      for (int tt = 0; tt < 4; ++tt) {
        float p0 = exp2f((st[qs][tt][0] - m_r[qs]) * CSC);
        float p1 = exp2f((st[qs][tt][1] - m_r[qs]) * CSC);
        float p2 = exp2f((st[qs][tt][2] - m_r[qs]) * CSC);
        float p3 = exp2f((st[qs][tt][3] - m_r[qs]) * CSC);
        ts[qs] += (p0 + p1) + (p2 + p3);
        char* base = (char*)Pw + (qs * 16 + c) * 128 + ((tt * 32 + g * 8) ^ kco);
        *(unsigned int*)(base) = pk2bf(p0, p1);
        *(unsigned int*)(base + 4) = pk2bf(p2, p3);
      }
      ts[qs] += __shfl_xor(ts[qs], 16, 64);
      ts[qs] += __shfl_xor(ts[qs], 32, 64);
      l_r[qs] += ts[qs];
    }

    // ---- PV: acc[qs][dc] += P[q][kv] * V^T[d][kv]
#pragma unroll
    for (int hh = 0; hh < 2; ++hh) {
      bf16x8 pa0 = *(const bf16x8*)((const char*)Pw + (c)*128 + ((hh * 64 + g * 16) ^ kco));
      bf16x8 pa1 = *(const bf16x8*)((const char*)Pw + (16 + c) * 128 + ((hh * 64 + g * 16) ^ kco));
      __builtin_amdgcn_s_setprio(1);
#pragma unroll
      for (int dc = 0; dc < 16; ++dc) {
        bf16x8 vf = *(const bf16x8*)&Vb[bb][(dc * 16 + c) * 64 +
                                            (((hh * 64 + g * 16) ^ kco) >> 1)];
        acc[0][dc] = __builtin_amdgcn_mfma_f32_16x16x32_bf16(pa0, vf, acc[0][dc], 0, 0, 0);
        acc[1][dc] = __builtin_amdgcn_mfma_f32_16x16x32_bf16(pa1, vf, acc[1][dc], 0, 0, 0);
      }
      __builtin_amdgcn_s_setprio(0);
    }

    __syncthreads();  // staging of it+1 done; everyone done reading buf bb
  }

  // ---- epilogue: store UNNORMALIZED partials + (m,l)
  if (g == 0) {
#pragma unroll
    for (int qs = 0; qs < 2; ++qs) {
      int row = q0 + w * 32 + qs * 16 + c;
      ML[((size_t)h * 16384 + row) * 2 + 0] = m_r[qs];
      ML[((size_t)h * 16384 + row) * 2 + 1] = l_r[qs];
    }
  }
  unsigned short* Pb = (h == 0) ? attnPO0 : (PO123 + (size_t)(h - 1) * 16384 * 256);
#pragma unroll
  for (int qs = 0; qs < 2; ++qs) {
#pragma unroll
    for (int dc = 0; dc < 16; ++dc) {
#pragma unroll
      for (int r = 0; r < 4; ++r) {
        int row = q0 + w * 32 + qs * 16 + 4 * g + r;
        Pb[(size_t)row * 256 + dc * 16 + c] = f2bf(acc[qs][dc][r]);
      }
    }
  }
}

// ---- kernel 3b: merge the four kv-quarter partials -> attn (bf16, in-place over PO0) ----
__global__ __launch_bounds__(256) void k_merge(unsigned short* __restrict__ attnPO0,
                                               const unsigned short* __restrict__ PO123,
                                               const float* __restrict__ ML) {
  int row = blockIdx.x * 4 + (threadIdx.x >> 6);
  int d4 = (threadIdx.x & 63) * 4;
  float m[4], l[4];
#pragma unroll
  for (int i = 0; i < 4; ++i) {
    m[i] = ML[((size_t)i * 16384 + row) * 2 + 0];
    l[i] = ML[((size_t)i * 16384 + row) * 2 + 1];
  }
  float ms = fmaxf(fmaxf(m[0], m[1]), fmaxf(m[2], m[3]));
  float a[4], lsum = 0.f;
#pragma unroll
  for (int i = 0; i < 4; ++i) {
    a[i] = exp2f((m[i] - ms) * CSC);
    lsum += l[i] * a[i];
  }
  float il = 1.f / lsum;
  float s0 = 0.f, s1 = 0.f, s2 = 0.f, s3 = 0.f;
#pragma unroll
  for (int i = 0; i < 4; ++i) {
    const unsigned short* src = (i == 0) ? attnPO0 : (PO123 + (size_t)(i - 1) * 16384 * 256);
    ushort4 u = *(const ushort4*)(src + (size_t)row * 256 + d4);
    s0 += bf2f(u.x) * a[i];
    s1 += bf2f(u.y) * a[i];
    s2 += bf2f(u.z) * a[i];
    s3 += bf2f(u.w) * a[i];
  }
  ushort4 o;
  o.x = f2bf(s0 * il);
  o.y = f2bf(s1 * il);
  o.z = f2bf(s2 * il);
  o.w = f2bf(s3 * il);
  *(ushort4*)(attnPO0 + (size_t)row * 256 + d4) = o;
}

// ---- kernel 4: out[m][o] = scale[o] * sum_d attn[m][d] * Wint[o][d] ----
__global__ __launch_bounds__(64) void k_gemm(const unsigned short* __restrict__ attn,
                                             const unsigned short* __restrict__ wbf,
                                             const float* __restrict__ scale,
                                             float* __restrict__ out) {
  int lane = threadIdx.x, g = lane >> 4, c = lane & 15;
  int m0 = blockIdx.x * 16;
  int o0 = blockIdx.y * 64;
  bf16x8 af[8];
#pragma unroll
  for (int dk = 0; dk < 8; ++dk)
    af[dk] = *(const bf16x8*)(attn + (m0 + c) * D + dk * 32 + g * 8);
  const f32x4 zero = {0.f, 0.f, 0.f, 0.f};
  f32x4 acc[4];
#pragma unroll
  for (int i = 0; i < 4; ++i) acc[i] = zero;
#pragma unroll
  for (int oc = 0; oc < 4; ++oc) {
#pragma unroll
    for (int dk = 0; dk < 8; ++dk) {
      bf16x8 wf = *(const bf16x8*)(wbf + (o0 + oc * 16 + c) * D + dk * 32 + g * 8);
      acc[oc] = __builtin_amdgcn_mfma_f32_16x16x32_bf16(af[dk], wf, acc[oc], 0, 0, 0);
    }
  }
#pragma unroll
  for (int oc = 0; oc < 4; ++oc) {
    float sc = scale[o0 + oc * 16 + c];
#pragma unroll
    for (int r = 0; r < 4; ++r)
      out[(m0 + 4 * g + r) * D + o0 + oc * 16 + c] = acc[oc][r] * sc;
  }
}

extern "C" void kernel_launch(void* const* d_in, const int* in_sizes, int n_in,
                              void* d_out, int out_size, void* d_ws, size_t ws_size,
                              hipStream_t stream) {
  (void)in_sizes; (void)n_in; (void)out_size; (void)ws_size;
  const float* x = (const float*)d_in[0];
  const int* w_int = (const int*)d_in[1];
  const float* scale = (const float*)d_in[2];
  float* out = (float*)d_out;

  char* ws = (char*)d_ws;
  unsigned short* xbf   = (unsigned short*)(ws);              // 8 MB
  unsigned short* xT    = (unsigned short*)(ws + 8388608);    // 8 MB
  unsigned short* attn  = (unsigned short*)(ws + 16777216);   // 8 MB (= PO quarter 0)
  unsigned short* wbf   = (unsigned short*)(ws + 25165824);   // 128 KB
  float*          ML    = (float*)(ws + 25296896);            // 512 KB (4x16384x2 f32)
  unsigned short* PO123 = (unsigned short*)(ws + 25821184);   // 24 MB (3x16384x256 bf16)

  k_prep<<<dim3(1024), dim3(256), 0, stream>>>(x, xbf, xT);
  k_deqw<<<dim3(256), dim3(256), 0, stream>>>(w_int, wbf);
  k_attn<<<dim3(256), dim3(512), 0, stream>>>(xbf, xT, attn, PO123, ML);
  k_merge<<<dim3(4096), dim3(256), 0, stream>>>(attn, PO123, ML);
  k_gemm<<<dim3(1024, 4), dim3(64), 0, stream>>>(attn, wbf, scale, out);
}